// Round 1
// baseline (1289.309 us; speedup 1.0000x reference)
//
#include <hip/hip_runtime.h>

typedef unsigned short u16;
typedef unsigned int u32;
typedef __attribute__((ext_vector_type(8))) short short8;
typedef __attribute__((ext_vector_type(4))) float floatx4;

#define SCALE_Q 0.17677669529663687f  // 32^-0.5

__device__ __forceinline__ u16 f2bf(float f) {
  u32 u = __float_as_uint(f);
  u = (u + 0x7fffu + ((u >> 16) & 1u)) >> 16;
  return (u16)u;
}

__device__ __forceinline__ void gload_lds16(const void* g, void* l) {
  __builtin_amdgcn_global_load_lds(
      (const __attribute__((address_space(1))) u32*)g,
      (__attribute__((address_space(3))) u32*)l, 16, 0, 0);
}

__device__ __forceinline__ floatx4 mfma16(short8 a, short8 b, floatx4 c) {
  return __builtin_amdgcn_mfma_f32_16x16x32_bf16(a, b, c, 0, 0, 0);
}

// ---------------- prep: cast weights to bf16 ----------------
__global__ void cast_w_kernel(const float* __restrict__ qkv_w,
                              const float* __restrict__ proj_w,
                              u16* __restrict__ wb1, u16* __restrict__ wb2) {
  int idx = blockIdx.x * 256 + threadIdx.x;   // grid covers 442368 exactly
  wb1[idx] = f2bf(qkv_w[idx]);
  if (idx < 147456) wb2[idx] = f2bf(proj_w[idx]);
}

// ---- prep: combined bias+mask table, transposed+padded: comb[w][h][q(64)][p(64)] ----
__global__ void comb_kernel(const float* __restrict__ bias_table,
                            const float* __restrict__ mask,
                            float* __restrict__ comb) {
  int wh = blockIdx.x;          // 768 = 64 windows * 12 heads
  int w = wh / 12, h = wh - w * 12;
  float* dst = comb + (size_t)wh * 4096;
  for (int e = threadIdx.x; e < 4096; e += 256) {
    int q = e >> 6, p = e & 63;
    float v;
    if (q >= 49) v = -1e30f;          // padded key columns -> softmax zero
    else if (p >= 49) v = 0.0f;       // padded query rows: keep finite
    else {
      int pi = p / 7, pj = p - pi * 7;
      int qi = q / 7, qj = q - qi * 7;
      int ridx = (pi - qi + 6) * 13 + (pj - qj + 6);
      v = bias_table[ridx * 12 + h] + mask[(size_t)w * 2401 + p * 49 + q];
    }
    dst[e] = v;                       // e = q*64 + p (transposed for float4 reads)
  }
}

// ---------------- QKV GEMM: (200704x384 fp32) @ (1152x384 bf16)^T + b ----------------
// 128x128 tile, 4 waves, each wave 64x64 via 4x4 frags of 16x16x32 bf16 MFMA, BK=32.
__global__ __launch_bounds__(256) void qkv_gemm(const float* __restrict__ A,
                                                const u16* __restrict__ B,
                                                const float* __restrict__ bias,
                                                u16* __restrict__ C) {
  __shared__ u16 As[128 * 32];
  __shared__ u16 Bs[128 * 32];
  const int tid = threadIdx.x;
  const int lane = tid & 63;
  const int wave = tid >> 6;
  const int l15 = lane & 15;
  const int quad = lane >> 4;
  const int wr = wave >> 1, wc = wave & 1;
  const int tn = blockIdx.x % 9;
  const int tm = blockIdx.x / 9;

  floatx4 acc[4][4];
#pragma unroll
  for (int i = 0; i < 4; ++i)
#pragma unroll
    for (int j = 0; j < 4; ++j) acc[i][j] = (floatx4){0.f, 0.f, 0.f, 0.f};

  for (int kb = 0; kb < 12; ++kb) {
    const int k0 = kb * 32;
    // stage A: fp32 -> bf16, 512 chunks of 8 elems (c = m*4 + kp)
#pragma unroll
    for (int cc = 0; cc < 2; ++cc) {
      const int c = tid + cc * 256;
      const int m = c >> 2, kp = c & 3;
      const float* ap = A + (size_t)(tm * 128 + m) * 384 + k0 + kp * 8;
      const float4 f0 = *(const float4*)ap;
      const float4 f1 = *(const float4*)(ap + 4);
      uint4 pk;
      pk.x = (u32)f2bf(f0.x) | ((u32)f2bf(f0.y) << 16);
      pk.y = (u32)f2bf(f0.z) | ((u32)f2bf(f0.w) << 16);
      pk.z = (u32)f2bf(f1.x) | ((u32)f2bf(f1.y) << 16);
      pk.w = (u32)f2bf(f1.z) | ((u32)f2bf(f1.w) << 16);
      *(uint4*)(&As[c * 8]) = pk;
    }
    // stage B: bf16 direct-to-LDS
#pragma unroll
    for (int r = 0; r < 2; ++r) {
      const int c = r * 256 + tid;
      const int n = c >> 2, kp = c & 3;
      gload_lds16(B + (size_t)(tn * 128 + n) * 384 + k0 + kp * 8, &Bs[c * 8]);
    }
    __syncthreads();
    short8 af[4], bfr[4];
#pragma unroll
    for (int i = 0; i < 4; ++i)
      af[i] = *(const short8*)(&As[(wr * 64 + i * 16 + l15) * 32 + quad * 8]);
#pragma unroll
    for (int i = 0; i < 4; ++i)
      bfr[i] = *(const short8*)(&Bs[(wc * 64 + i * 16 + l15) * 32 + quad * 8]);
#pragma unroll
    for (int mi = 0; mi < 4; ++mi)
#pragma unroll
      for (int ni = 0; ni < 4; ++ni)
        acc[mi][ni] = mfma16(af[mi], bfr[ni], acc[mi][ni]);
    __syncthreads();
  }
  // epilogue: +bias, fold SCALE into q (tn<3 <=> col<384)
  const float scale = (tn < 3) ? SCALE_Q : 1.0f;
#pragma unroll
  for (int ni = 0; ni < 4; ++ni) {
    const int gcol = tn * 128 + wc * 64 + ni * 16 + l15;
    const float bb = bias[gcol];
#pragma unroll
    for (int mi = 0; mi < 4; ++mi) {
      const int grow0 = tm * 128 + wr * 64 + mi * 16 + quad * 4;
#pragma unroll
      for (int r = 0; r < 4; ++r)
        C[(size_t)(grow0 + r) * 1152 + gcol] = f2bf((acc[mi][ni][r] + bb) * scale);
    }
  }
}

// ---------------- attention: one wave per (window, head) ----------------
// LDS: Qs 64x56 bf16 @0 (7168B), Ks @7168, Vt 32x72 @14336 (4608B); Ps 64x72 overlaps Q/K.
__global__ __launch_bounds__(64) void attn_kernel(const u16* __restrict__ qkv,
                                                  const float* __restrict__ comb,
                                                  u16* __restrict__ ao) {
  __shared__ uint4 smem4[1184];  // 18944 B
  char* smem = (char*)smem4;
  u16* Qs = (u16*)smem;
  u16* Ks = (u16*)(smem + 7168);
  u16* Vt = (u16*)(smem + 14336);
  u16* Ps = (u16*)smem;

  const int tid = threadIdx.x;
  const int l15 = tid & 15, quad = tid >> 4;
  const int bh = blockIdx.x;
  const int b = bh / 12, h = bh - b * 12;
  const int w = b & 63;

  // zero pad regions (Q rows>=49, K rows>=49, all of Vt)
  const uint4 z = make_uint4(0u, 0u, 0u, 0u);
  for (int i = tid; i < 105; i += 64) smem4[343 + i] = z;          // 5488/16=343
  for (int i = tid; i < 105; i += 64) smem4[791 + i] = z;          // (7168+5488)/16
  for (int i = tid; i < 288; i += 64) smem4[896 + i] = z;          // 14336/16
  __syncthreads();

  // load Q,K into LDS rows; V transposed (Vt[d][t])
  const size_t base = (size_t)b * 49 * 1152 + (size_t)h * 32;
  for (int s0 = tid; s0 < 196; s0 += 64) {
    const int t = s0 >> 2, part = s0 & 3;
    const u16* g = qkv + base + (size_t)t * 1152 + part * 8;
    const uint4 dq = *(const uint4*)(g);
    const uint4 dk = *(const uint4*)(g + 384);
    const uint4 dv = *(const uint4*)(g + 768);
    *(uint4*)(Qs + t * 56 + part * 8) = dq;
    *(uint4*)(Ks + t * 56 + part * 8) = dk;
    const int d0 = part * 8;
    const u32 vv[4] = {dv.x, dv.y, dv.z, dv.w};
#pragma unroll
    for (int j = 0; j < 4; ++j) {
      Vt[(d0 + 2 * j) * 72 + t] = (u16)(vv[j] & 0xffffu);
      Vt[(d0 + 2 * j + 1) * 72 + t] = (u16)(vv[j] >> 16);
    }
  }
  __syncthreads();

  // S = Q K^T (64x64 padded): 16 MFMAs
  short8 aq[4], bk[4];
#pragma unroll
  for (int i = 0; i < 4; ++i)
    aq[i] = *(const short8*)(Qs + (i * 16 + l15) * 56 + quad * 8);
#pragma unroll
  for (int i = 0; i < 4; ++i)
    bk[i] = *(const short8*)(Ks + (i * 16 + l15) * 56 + quad * 8);
  floatx4 s[4][4];
  const floatx4 z4 = (floatx4){0.f, 0.f, 0.f, 0.f};
#pragma unroll
  for (int mi = 0; mi < 4; ++mi)
#pragma unroll
    for (int ni = 0; ni < 4; ++ni) s[mi][ni] = mfma16(aq[mi], bk[ni], z4);

  // add combined bias+mask (stored [q][p] -> float4 over p/reg axis)
  const float* cb = comb + (size_t)(w * 12 + h) * 4096;
#pragma unroll
  for (int ni = 0; ni < 4; ++ni)
#pragma unroll
    for (int mi = 0; mi < 4; ++mi) {
      const float4 cv = *(const float4*)(cb + (ni * 16 + l15) * 64 + mi * 16 + quad * 4);
      s[mi][ni][0] += cv.x;
      s[mi][ni][1] += cv.y;
      s[mi][ni][2] += cv.z;
      s[mi][ni][3] += cv.w;
    }

  // online-free softmax (full row resident): row = mi*16 + quad*4 + r, cols across ni & l15
  floatx4 mx[4], sm[4];
#pragma unroll
  for (int mi = 0; mi < 4; ++mi)
#pragma unroll
    for (int r = 0; r < 4; ++r) {
      float m0 = fmaxf(fmaxf(s[mi][0][r], s[mi][1][r]), fmaxf(s[mi][2][r], s[mi][3][r]));
      mx[mi][r] = m0;
    }
#pragma unroll
  for (int d = 1; d < 16; d <<= 1)
#pragma unroll
    for (int mi = 0; mi < 4; ++mi)
#pragma unroll
      for (int r = 0; r < 4; ++r)
        mx[mi][r] = fmaxf(mx[mi][r], __shfl_xor(mx[mi][r], d));
#pragma unroll
  for (int mi = 0; mi < 4; ++mi)
#pragma unroll
    for (int r = 0; r < 4; ++r) {
      float a = 0.f;
#pragma unroll
      for (int ni = 0; ni < 4; ++ni) {
        const float e = __expf(s[mi][ni][r] - mx[mi][r]);
        s[mi][ni][r] = e;
        a += e;
      }
      sm[mi][r] = a;
    }
#pragma unroll
  for (int d = 1; d < 16; d <<= 1)
#pragma unroll
    for (int mi = 0; mi < 4; ++mi)
#pragma unroll
      for (int r = 0; r < 4; ++r)
        sm[mi][r] += __shfl_xor(sm[mi][r], d);

  __syncthreads();  // Q/K fully consumed; Ps overlaps that region
#pragma unroll
  for (int mi = 0; mi < 4; ++mi)
#pragma unroll
    for (int r = 0; r < 4; ++r) {
      const float rinv = 1.0f / sm[mi][r];
      const int row = mi * 16 + quad * 4 + r;
#pragma unroll
      for (int ni = 0; ni < 4; ++ni)
        Ps[row * 72 + ni * 16 + l15] = f2bf(s[mi][ni][r] * rinv);
    }
  __syncthreads();

  // O = P V : M=64(pad), N=32, K=64(pad) -> 16 MFMAs
  floatx4 o[4][2];
#pragma unroll
  for (int mi = 0; mi < 4; ++mi)
#pragma unroll
    for (int ni = 0; ni < 2; ++ni) o[mi][ni] = z4;
#pragma unroll
  for (int kk = 0; kk < 2; ++kk) {
    short8 ap[4], bv[2];
#pragma unroll
    for (int mi = 0; mi < 4; ++mi)
      ap[mi] = *(const short8*)(Ps + (mi * 16 + l15) * 72 + kk * 32 + quad * 8);
#pragma unroll
    for (int ni = 0; ni < 2; ++ni)
      bv[ni] = *(const short8*)(Vt + (ni * 16 + l15) * 72 + kk * 32 + quad * 8);
#pragma unroll
    for (int mi = 0; mi < 4; ++mi)
#pragma unroll
      for (int ni = 0; ni < 2; ++ni) o[mi][ni] = mfma16(ap[mi], bv[ni], o[mi][ni]);
  }
  // store ao (bf16), rows < 49 only
#pragma unroll
  for (int mi = 0; mi < 4; ++mi)
#pragma unroll
    for (int r = 0; r < 4; ++r) {
      const int row = mi * 16 + quad * 4 + r;
      if (row < 49) {
        u16* dst = ao + (size_t)(b * 49 + row) * 384 + h * 32;
#pragma unroll
        for (int ni = 0; ni < 2; ++ni)
          dst[ni * 16 + l15] = f2bf(o[mi][ni][r]);
      }
    }
}

// ---------------- proj GEMM: (200704x384 bf16) @ (384x384 bf16)^T + b -> fp32 ----------------
__global__ __launch_bounds__(256) void proj_gemm(const u16* __restrict__ A,
                                                 const u16* __restrict__ B,
                                                 const float* __restrict__ bias,
                                                 float* __restrict__ C) {
  __shared__ u16 As[128 * 32];
  __shared__ u16 Bs[128 * 32];
  const int tid = threadIdx.x;
  const int lane = tid & 63;
  const int wave = tid >> 6;
  const int l15 = lane & 15;
  const int quad = lane >> 4;
  const int wr = wave >> 1, wc = wave & 1;
  const int tn = blockIdx.x % 3;
  const int tm = blockIdx.x / 3;

  floatx4 acc[4][4];
#pragma unroll
  for (int i = 0; i < 4; ++i)
#pragma unroll
    for (int j = 0; j < 4; ++j) acc[i][j] = (floatx4){0.f, 0.f, 0.f, 0.f};

  for (int kb = 0; kb < 12; ++kb) {
    const int k0 = kb * 32;
#pragma unroll
    for (int r = 0; r < 2; ++r) {
      const int c = r * 256 + tid;
      const int m = c >> 2, kp = c & 3;
      gload_lds16(A + (size_t)(tm * 128 + m) * 384 + k0 + kp * 8, &As[c * 8]);
      gload_lds16(B + (size_t)(tn * 128 + m) * 384 + k0 + kp * 8, &Bs[c * 8]);
    }
    __syncthreads();
    short8 af[4], bfr[4];
#pragma unroll
    for (int i = 0; i < 4; ++i)
      af[i] = *(const short8*)(&As[(wr * 64 + i * 16 + l15) * 32 + quad * 8]);
#pragma unroll
    for (int i = 0; i < 4; ++i)
      bfr[i] = *(const short8*)(&Bs[(wc * 64 + i * 16 + l15) * 32 + quad * 8]);
#pragma unroll
    for (int mi = 0; mi < 4; ++mi)
#pragma unroll
      for (int ni = 0; ni < 4; ++ni)
        acc[mi][ni] = mfma16(af[mi], bfr[ni], acc[mi][ni]);
    __syncthreads();
  }
#pragma unroll
  for (int ni = 0; ni < 4; ++ni) {
    const int gcol = tn * 128 + wc * 64 + ni * 16 + l15;
    const float bb = bias[gcol];
#pragma unroll
    for (int mi = 0; mi < 4; ++mi) {
      const int grow0 = tm * 128 + wr * 64 + mi * 16 + quad * 4;
#pragma unroll
      for (int r = 0; r < 4; ++r)
        C[(size_t)(grow0 + r) * 384 + gcol] = acc[mi][ni][r] + bb;
    }
  }
}

// ---------------- launcher ----------------
extern "C" void kernel_launch(void* const* d_in, const int* in_sizes, int n_in,
                              void* d_out, int out_size, void* d_ws, size_t ws_size,
                              hipStream_t stream) {
  const float* x = (const float*)d_in[0];
  const float* mask = (const float*)d_in[1];
  const float* qkv_w = (const float*)d_in[2];
  const float* qkv_b = (const float*)d_in[3];
  const float* proj_w = (const float*)d_in[4];
  const float* proj_b = (const float*)d_in[5];
  const float* bias_table = (const float*)d_in[6];
  float* out = (float*)d_out;
  char* ws = (char*)d_ws;

  u16* wb1 = (u16*)(ws);                        // 442368 bf16 = 884736 B
  u16* wb2 = (u16*)(ws + 884736);               // 147456 bf16 = 294912 B
  float* comb = (float*)(ws + 1179648);         // 768*4096 f32 = 12582912 B
  u16* qkvb = (u16*)(ws + 13762560);            // 200704*1152 bf16 = 462422016 B
  u16* ao = (u16*)(ws + 476184576);             // 200704*384 bf16 = 154140672 B
  // total ws use: 630325248 B

  hipLaunchKernelGGL(cast_w_kernel, dim3(1728), dim3(256), 0, stream, qkv_w, proj_w, wb1, wb2);
  hipLaunchKernelGGL(comb_kernel, dim3(768), dim3(256), 0, stream, bias_table, mask, comb);
  hipLaunchKernelGGL(qkv_gemm, dim3(14112), dim3(256), 0, stream, x, wb1, qkv_b, qkvb);
  hipLaunchKernelGGL(attn_kernel, dim3(49152), dim3(64), 0, stream, qkvb, comb, ao);
  hipLaunchKernelGGL(proj_gemm, dim3(4704), dim3(256), 0, stream, ao, wb2, proj_b, out);
}

// Round 2
// 1209.821 us; speedup vs baseline: 1.0657x; 1.0657x over previous
//
#include <hip/hip_runtime.h>

typedef unsigned short u16;
typedef unsigned int u32;
typedef __attribute__((ext_vector_type(8))) short short8;
typedef __attribute__((ext_vector_type(4))) float floatx4;

#define SCALE_Q 0.17677669529663687f  // 32^-0.5

__device__ __forceinline__ u16 f2bf(float f) {
  u32 u = __float_as_uint(f);
  u = (u + 0x7fffu + ((u >> 16) & 1u)) >> 16;
  return (u16)u;
}

__device__ __forceinline__ void gload_lds16(const void* g, void* l) {
  __builtin_amdgcn_global_load_lds(
      (const __attribute__((address_space(1))) u32*)g,
      (__attribute__((address_space(3))) u32*)l, 16, 0, 0);
}

__device__ __forceinline__ floatx4 mfma16(short8 a, short8 b, floatx4 c) {
  return __builtin_amdgcn_mfma_f32_16x16x32_bf16(a, b, c, 0, 0, 0);
}

// ---------------- prep: cast weights to bf16 ----------------
__global__ void cast_w_kernel(const float* __restrict__ qkv_w,
                              const float* __restrict__ proj_w,
                              u16* __restrict__ wb1, u16* __restrict__ wb2) {
  int idx = blockIdx.x * 256 + threadIdx.x;   // grid covers 442368 exactly
  wb1[idx] = f2bf(qkv_w[idx]);
  if (idx < 147456) wb2[idx] = f2bf(proj_w[idx]);
}

// ---------------- prep: cast x to bf16 (8 elems/thread) ----------------
__global__ __launch_bounds__(256) void cast_x_kernel(const float* __restrict__ x,
                                                     u16* __restrict__ xb) {
  const size_t i = ((size_t)blockIdx.x * 256 + threadIdx.x) * 8;  // grid covers 77070336
  const float4 f0 = *(const float4*)(x + i);
  const float4 f1 = *(const float4*)(x + i + 4);
  uint4 pk;
  pk.x = (u32)f2bf(f0.x) | ((u32)f2bf(f0.y) << 16);
  pk.y = (u32)f2bf(f0.z) | ((u32)f2bf(f0.w) << 16);
  pk.z = (u32)f2bf(f1.x) | ((u32)f2bf(f1.y) << 16);
  pk.w = (u32)f2bf(f1.z) | ((u32)f2bf(f1.w) << 16);
  *(uint4*)(xb + i) = pk;
}

// ---- prep: combined bias+mask table, transposed+padded: comb[w][h][key(64)][query(64)] ----
__global__ void comb_kernel(const float* __restrict__ bias_table,
                            const float* __restrict__ mask,
                            float* __restrict__ comb) {
  int wh = blockIdx.x;          // 768 = 64 windows * 12 heads
  int w = wh / 12, h = wh - w * 12;
  float* dst = comb + (size_t)wh * 4096;
  for (int e = threadIdx.x; e < 4096; e += 256) {
    int q = e >> 6, p = e & 63;   // q = key token, p = query token
    float v;
    if (q >= 49) v = -1e30f;          // padded key columns -> softmax zero
    else if (p >= 49) v = 0.0f;       // padded query rows: keep finite
    else {
      int pi = p / 7, pj = p - pi * 7;
      int qi = q / 7, qj = q - qi * 7;
      int ridx = (pi - qi + 6) * 13 + (pj - qj + 6);
      v = bias_table[ridx * 12 + h] + mask[(size_t)w * 2401 + p * 49 + q];
    }
    dst[e] = v;                       // e = key*64 + query (for float4 reads over reg axis)
  }
}

// ---------------- QKV GEMM: (200704x384 bf16) @ (1152x384 bf16)^T + b -> bf16 ----------------
// 128x128 tile, 4 waves, 4x4 frags of 16x16x32 bf16 MFMA, BK=32, both operands global_load_lds.
// XCD-grouped swizzle: all 9 tn tiles of a tm land on one XCD (A fetched ~once per XCD).
__global__ __launch_bounds__(256) void qkv_gemm(const u16* __restrict__ A,
                                                const u16* __restrict__ B,
                                                const float* __restrict__ bias,
                                                u16* __restrict__ C) {
  __shared__ u16 As[128 * 32];
  __shared__ u16 Bs[128 * 32];
  const int tid = threadIdx.x;
  const int lane = tid & 63;
  const int wave = tid >> 6;
  const int l15 = lane & 15;
  const int quad = lane >> 4;
  const int wr = wave >> 1, wc = wave & 1;
  // swizzle: grid 14112 = 8 xcd * 196 grp * 9 tn
  const u32 bid = blockIdx.x;
  const u32 xcd = bid & 7;
  const u32 slot = bid >> 3;        // 0..1763
  const u32 grp = slot / 9;
  const u32 tn = slot - grp * 9;
  const u32 tm = xcd * 196 + grp;   // 0..1567

  floatx4 acc[4][4];
#pragma unroll
  for (int i = 0; i < 4; ++i)
#pragma unroll
    for (int j = 0; j < 4; ++j) acc[i][j] = (floatx4){0.f, 0.f, 0.f, 0.f};

  for (int kb = 0; kb < 12; ++kb) {
    const int k0 = kb * 32;
#pragma unroll
    for (int r = 0; r < 2; ++r) {
      const int c = r * 256 + tid;
      const int m = c >> 2, kp = c & 3;
      gload_lds16(A + (size_t)(tm * 128 + m) * 384 + k0 + kp * 8, &As[c * 8]);
      gload_lds16(B + (size_t)(tn * 128 + m) * 384 + k0 + kp * 8, &Bs[c * 8]);
    }
    __syncthreads();
    short8 af[4], bfr[4];
#pragma unroll
    for (int i = 0; i < 4; ++i)
      af[i] = *(const short8*)(&As[(wr * 64 + i * 16 + l15) * 32 + quad * 8]);
#pragma unroll
    for (int i = 0; i < 4; ++i)
      bfr[i] = *(const short8*)(&Bs[(wc * 64 + i * 16 + l15) * 32 + quad * 8]);
#pragma unroll
    for (int mi = 0; mi < 4; ++mi)
#pragma unroll
      for (int ni = 0; ni < 4; ++ni)
        acc[mi][ni] = mfma16(af[mi], bfr[ni], acc[mi][ni]);
    __syncthreads();
  }
  // epilogue: +bias, fold SCALE into q (tn<3 <=> col<384)
  const float scale = (tn < 3) ? SCALE_Q : 1.0f;
#pragma unroll
  for (int ni = 0; ni < 4; ++ni) {
    const int gcol = tn * 128 + wc * 64 + ni * 16 + l15;
    const float bb = bias[gcol];
#pragma unroll
    for (int mi = 0; mi < 4; ++mi) {
      const int grow0 = tm * 128 + wr * 64 + mi * 16 + quad * 4;
#pragma unroll
      for (int r = 0; r < 4; ++r)
        C[(size_t)(grow0 + r) * 1152 + gcol] = f2bf((acc[mi][ni][r] + bb) * scale);
    }
  }
}

// ---------------- attention: one wave per (window, head) ----------------
// Q/K MFMA frags loaded straight from global (lane=row, 16B contiguous per lane).
// LDS: Ps 64x72 bf16 @0 (9216B), Vt 32x72 bf16 @9216 (4608B) -> 13824 B/block.
__global__ __launch_bounds__(64) void attn_kernel(const u16* __restrict__ qkv,
                                                  const float* __restrict__ comb,
                                                  u16* __restrict__ ao) {
  __shared__ uint4 smem4[864];
  u16* Ps = (u16*)smem4;
  u16* Vt = (u16*)((char*)smem4 + 9216);

  const int tid = threadIdx.x;
  const int l15 = tid & 15, quad = tid >> 4;
  const int bh = blockIdx.x;
  const int b = bh / 12, h = bh - b * 12;
  const int w = b & 63;

  // zero all of Vt (pad tokens 49..71 must be exactly 0; avoid stale-LDS NaN x 0)
  const uint4 z = make_uint4(0u, 0u, 0u, 0u);
  for (int i = tid; i < 288; i += 64) smem4[576 + i] = z;  // 9216/16 = 576

  // V load + transpose into Vt[d][t]
  const size_t base = (size_t)b * 49 * 1152 + (size_t)h * 32;
  const u16* vbase = qkv + base + 768;
  for (int s0 = tid; s0 < 196; s0 += 64) {
    const int t = s0 >> 2, part = s0 & 3;
    const uint4 dv = *(const uint4*)(vbase + (size_t)t * 1152 + part * 8);
    const int d0 = part * 8;
    const u32 vv[4] = {dv.x, dv.y, dv.z, dv.w};
#pragma unroll
    for (int j = 0; j < 4; ++j) {
      Vt[(d0 + 2 * j) * 72 + t] = (u16)(vv[j] & 0xffffu);
      Vt[(d0 + 2 * j + 1) * 72 + t] = (u16)(vv[j] >> 16);
    }
  }

  // Q/K frags direct from global: row = i*16+l15 (token), dims quad*8..+8
  const u16* qbase = qkv + base + quad * 8;
  short8 aq[4], bk[4];
  const short8 z8 = {0, 0, 0, 0, 0, 0, 0, 0};
#pragma unroll
  for (int i = 0; i < 3; ++i) {
    aq[i] = *(const short8*)(qbase + (size_t)(i * 16 + l15) * 1152);
    bk[i] = *(const short8*)(qbase + 384 + (size_t)(i * 16 + l15) * 1152);
  }
  aq[3] = (l15 == 0) ? *(const short8*)(qbase + (size_t)48 * 1152) : z8;
  bk[3] = (l15 == 0) ? *(const short8*)(qbase + 384 + (size_t)48 * 1152) : z8;

  // S = Q K^T (64x64 padded): 16 MFMAs.  C-layout: col=key=ni*16+l15, row=query=mi*16+quad*4+r
  floatx4 s[4][4];
  const floatx4 z4 = (floatx4){0.f, 0.f, 0.f, 0.f};
#pragma unroll
  for (int mi = 0; mi < 4; ++mi)
#pragma unroll
    for (int ni = 0; ni < 4; ++ni) s[mi][ni] = mfma16(aq[mi], bk[ni], z4);

  // add combined bias+mask: comb[key*64 + query], float4 over query/reg axis
  const float* cb = comb + (size_t)(w * 12 + h) * 4096;
#pragma unroll
  for (int ni = 0; ni < 4; ++ni)
#pragma unroll
    for (int mi = 0; mi < 4; ++mi) {
      const float4 cv = *(const float4*)(cb + (ni * 16 + l15) * 64 + mi * 16 + quad * 4);
      s[mi][ni][0] += cv.x;
      s[mi][ni][1] += cv.y;
      s[mi][ni][2] += cv.z;
      s[mi][ni][3] += cv.w;
    }

  // softmax: rows resident, cols across {ni, l15} -> 16-lane shuffle reduce
  floatx4 mx[4], sm[4];
#pragma unroll
  for (int mi = 0; mi < 4; ++mi)
#pragma unroll
    for (int r = 0; r < 4; ++r)
      mx[mi][r] = fmaxf(fmaxf(s[mi][0][r], s[mi][1][r]), fmaxf(s[mi][2][r], s[mi][3][r]));
#pragma unroll
  for (int d = 1; d < 16; d <<= 1)
#pragma unroll
    for (int mi = 0; mi < 4; ++mi)
#pragma unroll
      for (int r = 0; r < 4; ++r)
        mx[mi][r] = fmaxf(mx[mi][r], __shfl_xor(mx[mi][r], d));
#pragma unroll
  for (int mi = 0; mi < 4; ++mi)
#pragma unroll
    for (int r = 0; r < 4; ++r) {
      float a = 0.f;
#pragma unroll
      for (int ni = 0; ni < 4; ++ni) {
        const float e = __expf(s[mi][ni][r] - mx[mi][r]);
        s[mi][ni][r] = e;
        a += e;
      }
      sm[mi][r] = a;
    }
#pragma unroll
  for (int d = 1; d < 16; d <<= 1)
#pragma unroll
    for (int mi = 0; mi < 4; ++mi)
#pragma unroll
      for (int r = 0; r < 4; ++r)
        sm[mi][r] += __shfl_xor(sm[mi][r], d);

  // P -> LDS (bf16, A-operand layout round trip)
#pragma unroll
  for (int mi = 0; mi < 4; ++mi)
#pragma unroll
    for (int r = 0; r < 4; ++r) {
      const float rinv = 1.0f / sm[mi][r];
      const int row = mi * 16 + quad * 4 + r;
#pragma unroll
      for (int ni = 0; ni < 4; ++ni)
        Ps[row * 72 + ni * 16 + l15] = f2bf(s[mi][ni][r] * rinv);
    }
  __syncthreads();  // orders Vt writes + Ps writes before reads

  // O = P V : M=64(pad), N=32, K=64(pad) -> 16 MFMAs
  floatx4 o[4][2];
#pragma unroll
  for (int mi = 0; mi < 4; ++mi)
#pragma unroll
    for (int ni = 0; ni < 2; ++ni) o[mi][ni] = z4;
#pragma unroll
  for (int kk = 0; kk < 2; ++kk) {
    short8 ap[4], bv[2];
#pragma unroll
    for (int mi = 0; mi < 4; ++mi)
      ap[mi] = *(const short8*)(Ps + (mi * 16 + l15) * 72 + kk * 32 + quad * 8);
#pragma unroll
    for (int ni = 0; ni < 2; ++ni)
      bv[ni] = *(const short8*)(Vt + (ni * 16 + l15) * 72 + kk * 32 + quad * 8);
#pragma unroll
    for (int mi = 0; mi < 4; ++mi)
#pragma unroll
      for (int ni = 0; ni < 2; ++ni) o[mi][ni] = mfma16(ap[mi], bv[ni], o[mi][ni]);
  }
  // store ao (bf16), rows < 49 only
#pragma unroll
  for (int mi = 0; mi < 4; ++mi)
#pragma unroll
    for (int r = 0; r < 4; ++r) {
      const int row = mi * 16 + quad * 4 + r;
      if (row < 49) {
        u16* dst = ao + (size_t)(b * 49 + row) * 384 + h * 32;
#pragma unroll
        for (int ni = 0; ni < 2; ++ni)
          dst[ni * 16 + l15] = f2bf(o[mi][ni][r]);
      }
    }
}

// ---------------- proj GEMM: (200704x384 bf16) @ (384x384 bf16)^T + b -> fp32 ----------------
__global__ __launch_bounds__(256) void proj_gemm(const u16* __restrict__ A,
                                                 const u16* __restrict__ B,
                                                 const float* __restrict__ bias,
                                                 float* __restrict__ C) {
  __shared__ u16 As[128 * 32];
  __shared__ u16 Bs[128 * 32];
  const int tid = threadIdx.x;
  const int lane = tid & 63;
  const int wave = tid >> 6;
  const int l15 = lane & 15;
  const int quad = lane >> 4;
  const int wr = wave >> 1, wc = wave & 1;
  // swizzle: grid 4704 = 8 xcd * 196 grp * 3 tn
  const u32 bid = blockIdx.x;
  const u32 xcd = bid & 7;
  const u32 slot = bid >> 3;        // 0..587
  const u32 grp = slot / 3;
  const u32 tn = slot - grp * 3;
  const u32 tm = xcd * 196 + grp;

  floatx4 acc[4][4];
#pragma unroll
  for (int i = 0; i < 4; ++i)
#pragma unroll
    for (int j = 0; j < 4; ++j) acc[i][j] = (floatx4){0.f, 0.f, 0.f, 0.f};

  for (int kb = 0; kb < 12; ++kb) {
    const int k0 = kb * 32;
#pragma unroll
    for (int r = 0; r < 2; ++r) {
      const int c = r * 256 + tid;
      const int m = c >> 2, kp = c & 3;
      gload_lds16(A + (size_t)(tm * 128 + m) * 384 + k0 + kp * 8, &As[c * 8]);
      gload_lds16(B + (size_t)(tn * 128 + m) * 384 + k0 + kp * 8, &Bs[c * 8]);
    }
    __syncthreads();
    short8 af[4], bfr[4];
#pragma unroll
    for (int i = 0; i < 4; ++i)
      af[i] = *(const short8*)(&As[(wr * 64 + i * 16 + l15) * 32 + quad * 8]);
#pragma unroll
    for (int i = 0; i < 4; ++i)
      bfr[i] = *(const short8*)(&Bs[(wc * 64 + i * 16 + l15) * 32 + quad * 8]);
#pragma unroll
    for (int mi = 0; mi < 4; ++mi)
#pragma unroll
      for (int ni = 0; ni < 4; ++ni)
        acc[mi][ni] = mfma16(af[mi], bfr[ni], acc[mi][ni]);
    __syncthreads();
  }
#pragma unroll
  for (int ni = 0; ni < 4; ++ni) {
    const int gcol = tn * 128 + wc * 64 + ni * 16 + l15;
    const float bb = bias[gcol];
#pragma unroll
    for (int mi = 0; mi < 4; ++mi) {
      const int grow0 = tm * 128 + wr * 64 + mi * 16 + quad * 4;
#pragma unroll
      for (int r = 0; r < 4; ++r)
        C[(size_t)(grow0 + r) * 384 + gcol] = acc[mi][ni][r] + bb;
    }
  }
}

// ---------------- launcher ----------------
extern "C" void kernel_launch(void* const* d_in, const int* in_sizes, int n_in,
                              void* d_out, int out_size, void* d_ws, size_t ws_size,
                              hipStream_t stream) {
  const float* x = (const float*)d_in[0];
  const float* mask = (const float*)d_in[1];
  const float* qkv_w = (const float*)d_in[2];
  const float* qkv_b = (const float*)d_in[3];
  const float* proj_w = (const float*)d_in[4];
  const float* proj_b = (const float*)d_in[5];
  const float* bias_table = (const float*)d_in[6];
  float* out = (float*)d_out;
  char* ws = (char*)d_ws;

  u16* wb1 = (u16*)(ws);                        // 442368 bf16 = 884736 B
  u16* wb2 = (u16*)(ws + 884736);               // 147456 bf16 = 294912 B
  float* comb = (float*)(ws + 1179648);         // 768*4096 f32 = 12582912 B
  u16* qkvb = (u16*)(ws + 13762560);            // 200704*1152 bf16 = 462422016 B
  u16* ao = (u16*)(ws + 476184576);             // 200704*384 bf16 = 154140672 B
  u16* xb = ao;                                 // xb dead before attn writes ao: share slot
  // total ws use: 630325248 B

  hipLaunchKernelGGL(cast_w_kernel, dim3(1728), dim3(256), 0, stream, qkv_w, proj_w, wb1, wb2);
  hipLaunchKernelGGL(cast_x_kernel, dim3(37632), dim3(256), 0, stream, x, xb);
  hipLaunchKernelGGL(comb_kernel, dim3(768), dim3(256), 0, stream, bias_table, mask, comb);
  hipLaunchKernelGGL(qkv_gemm, dim3(14112), dim3(256), 0, stream, xb, wb1, qkv_b, qkvb);
  hipLaunchKernelGGL(attn_kernel, dim3(49152), dim3(64), 0, stream, qkvb, comb, ao);
  hipLaunchKernelGGL(proj_gemm, dim3(4704), dim3(256), 0, stream, ao, wb2, proj_b, out);
}